// Round 8
// baseline (580.890 us; speedup 1.0000x reference)
//
#include <hip/hip_runtime.h>
#include <stdint.h>

#define NN 100000   // nodes
#define NK 10       // sampled neighbors
#define D  256      // hidden dim
#define D2 512      // concat dim
#define MT 32       // nodes per GEMM block; 100000/32 = 3125 exact
#define GR 8        // rows per gather block; 100000/8 = 12500 exact

typedef short bf16x8 __attribute__((ext_vector_type(8)));   // 8 bf16 (4 VGPRs)
typedef float f32x4  __attribute__((ext_vector_type(4)));

__device__ __forceinline__ uint16_t f2bf(float f) {
  uint32_t u = __float_as_uint(f);
  u += 0x7fffu + ((u >> 16) & 1u);   // round-to-nearest-even
  return (uint16_t)(u >> 16);
}
__device__ __forceinline__ uint32_t pack2(float a, float b) {
  return (uint32_t)f2bf(a) | ((uint32_t)f2bf(b) << 16);
}

// ---------------------------------------------------------------------------
// prep: fused {3x pack_w , quant_x} in one launch.
// ---------------------------------------------------------------------------
__global__ __launch_bounds__(256) void prep(
    const float* __restrict__ x, uint8_t* __restrict__ q8, float* __restrict__ qs,
    const float* __restrict__ W0, const float* __restrict__ W1,
    const float* __restrict__ W2, uint16_t* __restrict__ Wp0,
    uint16_t* __restrict__ Wp1, uint16_t* __restrict__ Wp2)
{
  const int bid = blockIdx.x;
  if (bid < 192) {
    const float* W;
    uint16_t* Wp;
    if (bid < 64)       { W = W0; Wp = Wp0; }
    else if (bid < 128) { W = W1; Wp = Wp1; }
    else                { W = W2; Wp = Wp2; }
    int idx   = ((bid & 63) << 8) + threadIdx.x;   // 0..16383
    int lane  = idx & 63;
    int ntile = (idx >> 6) & 15;
    int kstep = idx >> 10;
    int n  = ntile * 16 + (lane & 15);
    int k0 = kstep * 32 + (lane >> 4) * 8;
    float v[8];
#pragma unroll
    for (int j = 0; j < 8; j++) v[j] = W[(size_t)(k0 + j) * D + n];
    uint4 o;
    o.x = pack2(v[0], v[1]);
    o.y = pack2(v[2], v[3]);
    o.z = pack2(v[4], v[5]);
    o.w = pack2(v[6], v[7]);
    ((uint4*)Wp)[idx] = o;
  } else {
    int node = (bid - 192) * 4 + (threadIdx.x >> 6);
    int lane = threadIdx.x & 63;
    const float4 v = *(const float4*)(x + (size_t)node * D + lane * 4);
    float m = fmaxf(fmaxf(fabsf(v.x), fabsf(v.y)), fmaxf(fabsf(v.z), fabsf(v.w)));
#pragma unroll
    for (int d = 1; d < 64; d <<= 1) m = fmaxf(m, __shfl_xor(m, d, 64));
    float inv = m > 1e-30f ? 127.0f / m : 0.0f;
    int q0 = (int)rintf(v.x * inv), q1 = (int)rintf(v.y * inv);
    int q2 = (int)rintf(v.z * inv), q3 = (int)rintf(v.w * inv);
    uint32_t p = (uint32_t)(q0 & 0xff) | ((uint32_t)(q1 & 0xff) << 8) |
                 ((uint32_t)(q2 & 0xff) << 16) | ((uint32_t)(q3 & 0xff) << 24);
    ((uint32_t*)(q8 + (size_t)node * D))[lane] = p;
    if (lane == 0) qs[node] = m * (1.0f / 127.0f);
  }
}

// ---------------------------------------------------------------------------
// gather_mean: the ONLY random-access kernel. Per 32-lane half: one dest row,
// 10 int8 neighbor-row gathers + scales, mean in f32, write one coalesced
// mean row (bf16, or int8+scale when MEAN8). Working set = table 25.6 MB +
// adj 4 MB + mean-out << L3 256 MB -> gathers L3-served after first touch.
// FMA order identical to the old fused consume -> bf16 path is bit-identical.
// No LDS, ~32 VGPR -> 32 waves/CU; per-wave 20 loads in flight.
// ---------------------------------------------------------------------------
template <bool MEAN8>
__global__ __launch_bounds__(256, 8) void gather_mean(
    const uint8_t* __restrict__ qtab,   // int8 [NN][D]
    const float*   __restrict__ qsc,    // [NN]
    const int*     __restrict__ adj,    // [NN][NK]
    void*          __restrict__ mout,   // bf16 [NN][D] | int8 [NN][D]
    float*         __restrict__ msc)    // [NN] (MEAN8 only)
{
  const int half = threadIdx.x >> 5;    // 0..7
  const int l32  = threadIdx.x & 31;
  const int r    = blockIdx.x * GR + half;   // destination node

  const int* ap = adj + (size_t)r * NK;
  int av = ap[(l32 < NK) ? l32 : 0];    // lanes 0..9 hold the indices

  float a0=0.f,a1=0.f,a2=0.f,a3=0.f,a4=0.f,a5=0.f,a6=0.f,a7=0.f;
#pragma unroll
  for (int k = 0; k < NK; k++) {
    int nb  = __shfl(av, k, 32);        // broadcast within the half
    float s = qsc[nb];
    uint2 v = *(const uint2*)(qtab + (size_t)nb * D + l32 * 8);
    a0 += s * (float)(int8_t)(v.x);
    a1 += s * (float)(int8_t)(v.x >> 8);
    a2 += s * (float)(int8_t)(v.x >> 16);
    a3 += s * (float)(int8_t)(v.x >> 24);
    a4 += s * (float)(int8_t)(v.y);
    a5 += s * (float)(int8_t)(v.y >> 8);
    a6 += s * (float)(int8_t)(v.y >> 16);
    a7 += s * (float)(int8_t)(v.y >> 24);
  }
  const float sc = 1.0f / (float)NK;
  a0 *= sc; a1 *= sc; a2 *= sc; a3 *= sc;
  a4 *= sc; a5 *= sc; a6 *= sc; a7 *= sc;

  if constexpr (!MEAN8) {
    uint4 o;
    o.x = pack2(a0, a1); o.y = pack2(a2, a3);
    o.z = pack2(a4, a5); o.w = pack2(a6, a7);
    ((uint4*)((uint16_t*)mout + (size_t)r * D))[l32] = o;   // 512B/row coalesced
  } else {
    float m = fmaxf(fmaxf(fmaxf(fabsf(a0), fabsf(a1)), fmaxf(fabsf(a2), fabsf(a3))),
                    fmaxf(fmaxf(fabsf(a4), fabsf(a5)), fmaxf(fabsf(a6), fabsf(a7))));
#pragma unroll
    for (int d = 1; d < 32; d <<= 1) m = fmaxf(m, __shfl_xor(m, d, 32));
    float inv = m > 1e-30f ? 127.0f / m : 0.0f;
    int q0 = (int)rintf(a0 * inv), q1 = (int)rintf(a1 * inv);
    int q2 = (int)rintf(a2 * inv), q3 = (int)rintf(a3 * inv);
    int q4 = (int)rintf(a4 * inv), q5 = (int)rintf(a5 * inv);
    int q6 = (int)rintf(a6 * inv), q7 = (int)rintf(a7 * inv);
    uint2 o;
    o.x = (uint32_t)(q0 & 0xff) | ((uint32_t)(q1 & 0xff) << 8) |
          ((uint32_t)(q2 & 0xff) << 16) | ((uint32_t)(q3 & 0xff) << 24);
    o.y = (uint32_t)(q4 & 0xff) | ((uint32_t)(q5 & 0xff) << 8) |
          ((uint32_t)(q6 & 0xff) << 16) | ((uint32_t)(q7 & 0xff) << 24);
    ((uint2*)((uint8_t*)mout + (size_t)r * D))[l32] = o;
    if (l32 == 0) msc[r] = m * (1.0f / 127.0f);
  }
}

// ---------------------------------------------------------------------------
// sage_gemm: pure streaming layer kernel. Phase 1: self rows -> LDS chunks
// 0..31. Phase 2: mean rows (bf16 or int8+scale) -> chunks 32..63. GEMM +
// epilogue identical to the fused kernel. No gathers, no waits.
// LDS 32 KB, XOR swizzle on 16B chunks (0 conflicts).
// ---------------------------------------------------------------------------
template <bool SELF_F32, bool QOUT, bool MEAN8>
__global__ __launch_bounds__(256, 4) void sage_gemm(
    const void*     __restrict__ hin_v,  // self: f32 or bf16 [NN][D]
    const void*     __restrict__ mb_v,   // mean: bf16 or int8 [NN][D]
    const float*    __restrict__ msc,    // [NN] (MEAN8 only)
    const uint16_t* __restrict__ Wp,     // packed bf16 W [16][16][64][8]
    const float*    __restrict__ bias,   // [D]
    void*           __restrict__ hout_v, // bf16 (QOUT) / f32 (!QOUT)
    uint8_t*        __restrict__ q8out,  // int8 table out (QOUT)
    float*          __restrict__ qsout)  // row scales out (QOUT)
{
  __shared__ uint4 lds4[MT * 64];        // 32 rows * 64 chunks * 16B = 32 KB
  const int t  = threadIdx.x;
  const int m0 = blockIdx.x * MT;

  // ---- phase 1: self rows -> chunks 0..31 ----
#pragma unroll
  for (int i = 0; i < 4; i++) {
    int cidx = t + i * 256;
    int r = cidx >> 5, c = cidx & 31;
    int node = m0 + r;
    uint4 o;
    if constexpr (SELF_F32) {
      const float4* p = (const float4*)((const float*)hin_v + (size_t)node * D + c * 8);
      float4 v0 = p[0], v1 = p[1];
      o.x = pack2(v0.x, v0.y); o.y = pack2(v0.z, v0.w);
      o.z = pack2(v1.x, v1.y); o.w = pack2(v1.z, v1.w);
    } else {
      o = *(const uint4*)((const uint16_t*)hin_v + (size_t)node * D + c * 8);
    }
    lds4[r * 64 + (c ^ (r & 15))] = o;
  }

  // ---- phase 2: mean rows -> chunks 32..63 ----
#pragma unroll
  for (int i = 0; i < 4; i++) {
    int cidx = t + i * 256;
    int r = cidx >> 5, cp = cidx & 31;
    int node = m0 + r;
    uint4 o;
    if constexpr (!MEAN8) {
      o = *(const uint4*)((const uint16_t*)mb_v + (size_t)node * D + cp * 8);
    } else {
      uint2 v = *(const uint2*)((const uint8_t*)mb_v + (size_t)node * D + cp * 8);
      float s = msc[node];
      float b0 = s * (float)(int8_t)(v.x);
      float b1 = s * (float)(int8_t)(v.x >> 8);
      float b2 = s * (float)(int8_t)(v.x >> 16);
      float b3 = s * (float)(int8_t)(v.x >> 24);
      float b4 = s * (float)(int8_t)(v.y);
      float b5 = s * (float)(int8_t)(v.y >> 8);
      float b6 = s * (float)(int8_t)(v.y >> 16);
      float b7 = s * (float)(int8_t)(v.y >> 24);
      o.x = pack2(b0, b1); o.y = pack2(b2, b3);
      o.z = pack2(b4, b5); o.w = pack2(b6, b7);
    }
    int c = 32 + cp;
    lds4[r * 64 + (c ^ (r & 15))] = o;
  }

  __syncthreads();

  // ---- GEMM  [32 x 512] @ [512 x 256] ----
  const int w    = t >> 6;   // wave 0..3 -> output cols w*64 .. w*64+63
  const int l    = t & 63;
  const int quad = l >> 4;
  const int l16  = l & 15;

  f32x4 acc[2][4];
#pragma unroll
  for (int mt = 0; mt < 2; mt++)
#pragma unroll
    for (int nt = 0; nt < 4; nt++)
      acc[mt][nt] = (f32x4){0.f, 0.f, 0.f, 0.f};

  const uint4* wp4 = (const uint4*)Wp;

#pragma unroll 2
  for (int ks = 0; ks < 16; ks++) {
    bf16x8 af[2], bfr[4];
#pragma unroll
    for (int mt = 0; mt < 2; mt++) {
      int row = mt * 16 + l16;                 // A: m = lane&15
      int c   = ks * 4 + quad;                 // A: k = quad*8 + j
      af[mt] = *((const bf16x8*)&lds4[row * 64 + (c ^ (row & 15))]);
    }
#pragma unroll
    for (int nt = 0; nt < 4; nt++) {
      bfr[nt] = *((const bf16x8*)&wp4[(ks * 16 + (w * 4 + nt)) * 64 + l]);
    }
#pragma unroll
    for (int mt = 0; mt < 2; mt++)
#pragma unroll
      for (int nt = 0; nt < 4; nt++)
        acc[mt][nt] = __builtin_amdgcn_mfma_f32_16x16x32_bf16(
            af[mt], bfr[nt], acc[mt][nt], 0, 0, 0);
  }

  // ---- epilogue: bias (+ReLU), row-scale quant (QOUT), store ----
  float lmax[2][4];
#pragma unroll
  for (int mt = 0; mt < 2; mt++)
#pragma unroll
    for (int i = 0; i < 4; i++) lmax[mt][i] = 0.0f;

#pragma unroll
  for (int mt = 0; mt < 2; mt++)
#pragma unroll
    for (int nt = 0; nt < 4; nt++)
#pragma unroll
      for (int i = 0; i < 4; i++) {
        int col = w * 64 + nt * 16 + l16;      // C/D: col = lane&15
        float v = acc[mt][nt][i] + bias[col];
        if (QOUT) v = fmaxf(v, 0.0f);          // ReLU on layers 0,1
        acc[mt][nt][i] = v;
        if (QOUT) lmax[mt][i] = fmaxf(lmax[mt][i], v);
      }

  float inv[2][4];
  if (QOUT) {
#pragma unroll
    for (int d = 1; d < 16; d <<= 1)
#pragma unroll
      for (int mt = 0; mt < 2; mt++)
#pragma unroll
        for (int i = 0; i < 4; i++)
          lmax[mt][i] = fmaxf(lmax[mt][i], __shfl_xor(lmax[mt][i], d, 64));
    __syncthreads();                            // lds4 dead -> reuse for rowmax
    float* rmax = (float*)lds4;                 // [32 rows][4 waves]
    if (l16 == 0) {
#pragma unroll
      for (int mt = 0; mt < 2; mt++)
#pragma unroll
        for (int i = 0; i < 4; i++)
          rmax[(mt * 16 + quad * 4 + i) * 4 + w] = lmax[mt][i];
    }
    __syncthreads();
#pragma unroll
    for (int mt = 0; mt < 2; mt++)
#pragma unroll
      for (int i = 0; i < 4; i++) {
        int row = mt * 16 + quad * 4 + i;
        float m = fmaxf(fmaxf(rmax[row * 4 + 0], rmax[row * 4 + 1]),
                        fmaxf(rmax[row * 4 + 2], rmax[row * 4 + 3]));
        inv[mt][i] = m > 1e-30f ? 127.0f / m : 0.0f;
        if (w == 0 && l16 == 0) qsout[m0 + row] = m * (1.0f / 127.0f);
      }
  }

#pragma unroll
  for (int mt = 0; mt < 2; mt++)
#pragma unroll
    for (int i = 0; i < 4; i++) {
      int rr = m0 + mt * 16 + quad * 4 + i;     // C/D: row = quad*4 + reg
#pragma unroll
      for (int nt = 0; nt < 4; nt++) {
        int col = w * 64 + nt * 16 + l16;
        float v = acc[mt][nt][i];
        if (QOUT) {
          ((uint16_t*)hout_v)[(size_t)rr * D + col] = f2bf(v);
          int q = (int)rintf(v * inv[mt][i]);
          q8out[(size_t)rr * D + col] = (uint8_t)(q & 0xff);
        } else {
          ((float*)hout_v)[(size_t)rr * D + col] = v;
        }
      }
    }
}

extern "C" void kernel_launch(void* const* d_in, const int* in_sizes, int n_in,
                              void* d_out, int out_size, void* d_ws, size_t ws_size,
                              hipStream_t stream) {
  const float* x   = (const float*)d_in[0];
  const int*   adj = (const int*)d_in[1];
  const float* W0  = (const float*)d_in[2];
  const float* b0  = (const float*)d_in[3];
  const float* W1  = (const float*)d_in[4];
  const float* b1  = (const float*)d_in[5];
  const float* W2  = (const float*)d_in[6];
  const float* b2  = (const float*)d_in[7];
  float* out = (float*)d_out;

  // d_out scratch (102.4 MB), lifetime-checked vs the final f32 overwrite:
  //   A [0,51.2e6):      hA  bf16  (M0 w -> M1 r)
  //   B [51.2,76.8e6):   hA8 int8  (M0 w -> G1 r)
  //   C [76.8,102.4e6):  x8  int8  (prep w -> G0 r), then hB8 (M1 w -> G2 r)
  uint8_t*  dob = (uint8_t*)d_out;
  uint16_t* hA  = (uint16_t*)dob;
  uint8_t*  hA8 = dob + 51200000;
  uint8_t*  x8  = dob + 76800000;
  uint8_t*  hB8 = dob + 76800000;      // reuses C after x8 is dead

  // ws: Wp x3 (0.75 MB) + hB bf16 (51.2) + mean slot (51.2 bf16 | 25.6 int8,
  // reused across layers) + scales. bf16-mean needs ~104.8 MB; if ws is
  // smaller, fall back to int8 mean (~79.2 MB, today's footprint).
  uint16_t* ws  = (uint16_t*)d_ws;
  uint16_t* Wp0 = ws;
  uint16_t* Wp1 = Wp0 + D2 * D;
  uint16_t* Wp2 = Wp1 + D2 * D;
  uint16_t* hB  = Wp2 + D2 * D;                      // bf16 [NN][D]
  uint8_t*  wsb = (uint8_t*)(hB + (size_t)NN * D);   // mean slot base

  const size_t NEED_BF16 = 3u * D2 * D * 2 + (size_t)NN * D * 2   // Wp + hB
                         + (size_t)NN * D * 2                      // mean bf16
                         + 4u * NN * 4;                            // scales
  const bool M8 = (ws_size < NEED_BF16);

  void*  meanb = (void*)wsb;
  float* tail  = (float*)(wsb + (M8 ? (size_t)NN * D : (size_t)NN * D * 2));
  float* msc = tail;            // [NN] mean scales (MEAN8 only)
  float* xs  = msc + NN;
  float* hAs = xs + NN;
  float* hBs = hAs + NN;

  prep<<<192 + NN / 4, 256, 0, stream>>>(x, x8, xs, W0, W1, W2, Wp0, Wp1, Wp2);

  const int gg = NN / GR;       // 12500
  const int gm = NN / MT;       // 3125

  if (!M8) {
    gather_mean<false><<<gg, 256, 0, stream>>>(x8, xs, adj, meanb, msc);
    sage_gemm<true,  true,  false><<<gm, 256, 0, stream>>>(x,  meanb, msc, Wp0, b0, hA,  hA8, hAs);
    gather_mean<false><<<gg, 256, 0, stream>>>(hA8, hAs, adj, meanb, msc);
    sage_gemm<false, true,  false><<<gm, 256, 0, stream>>>(hA, meanb, msc, Wp1, b1, hB,  hB8, hBs);
    gather_mean<false><<<gg, 256, 0, stream>>>(hB8, hBs, adj, meanb, msc);
    sage_gemm<false, false, false><<<gm, 256, 0, stream>>>(hB, meanb, msc, Wp2, b2, out, nullptr, nullptr);
  } else {
    gather_mean<true><<<gg, 256, 0, stream>>>(x8, xs, adj, meanb, msc);
    sage_gemm<true,  true,  true><<<gm, 256, 0, stream>>>(x,  meanb, msc, Wp0, b0, hA,  hA8, hAs);
    gather_mean<true><<<gg, 256, 0, stream>>>(hA8, hAs, adj, meanb, msc);
    sage_gemm<false, true,  true><<<gm, 256, 0, stream>>>(hA, meanb, msc, Wp1, b1, hB,  hB8, hBs);
    gather_mean<true><<<gg, 256, 0, stream>>>(hB8, hBs, adj, meanb, msc);
    sage_gemm<false, false, true><<<gm, 256, 0, stream>>>(hB, meanb, msc, Wp2, b2, out, nullptr, nullptr);
  }
}